// Round 1
// baseline (102.690 us; speedup 1.0000x reference)
//
#include <hip/hip_runtime.h>
#include <math.h>

#define KMAX 512  // fixed by the benchmark shapes (16384 x 512)

// One wave (64 lanes) per row; 8 elements per lane (2x float4).
// 4 rows per 256-thread block. Writes per-block (sum, count) partials.
__global__ __launch_bounds__(256) void listnet_rows(
    const float* __restrict__ pred,
    const float* __restrict__ targ,
    const int*   __restrict__ lengths,
    float2*      __restrict__ partials,
    int B)
{
    const int wave = threadIdx.x >> 6;
    const int lane = threadIdx.x & 63;
    const int row  = blockIdx.x * 4 + wave;

    float per_row = 0.0f;
    float valid   = 0.0f;

    if (row < B) {
        const int L = lengths[row];
        if (L >= 2) {
            const int base = lane * 8;
            const int nv   = L - base;  // valid elems in this lane's chunk (<=0 means none)
            float p[8];
            float nt[8];
            if (nv > 0) {
                // base+8 <= 512 always (lane<=63), so full-width loads are in-bounds;
                // out-of-range elements are masked in registers below.
                const float4* p4 = reinterpret_cast<const float4*>(pred + (size_t)row * KMAX + base);
                const float4* t4 = reinterpret_cast<const float4*>(targ + (size_t)row * KMAX + base);
                float4 pa = p4[0], pb = p4[1];
                float4 ta = t4[0], tb = t4[1];
                p[0]=pa.x; p[1]=pa.y; p[2]=pa.z; p[3]=pa.w;
                p[4]=pb.x; p[5]=pb.y; p[6]=pb.z; p[7]=pb.w;
                nt[0]=-ta.x; nt[1]=-ta.y; nt[2]=-ta.z; nt[3]=-ta.w;
                nt[4]=-tb.x; nt[5]=-tb.y; nt[6]=-tb.z; nt[7]=-tb.w;
            }

            // per-lane maxima over valid elements only (avoids uninit/NaN reads)
            float mp = -INFINITY, mt = -INFINITY;
            #pragma unroll
            for (int j = 0; j < 8; ++j) {
                if (nv > j) { mp = fmaxf(mp, p[j]); mt = fmaxf(mt, nt[j]); }
            }
            // wave-wide max (L>=2 guarantees a finite max exists in the wave)
            #pragma unroll
            for (int off = 32; off > 0; off >>= 1) {
                mp = fmaxf(mp, __shfl_xor(mp, off, 64));
                mt = fmaxf(mt, __shfl_xor(mt, off, 64));
            }

            // sums: sp = sum exp(p-mp); st = sum exp(-t-mt); w = sum exp(-t-mt)*p
            float sp = 0.f, st = 0.f, w = 0.f;
            #pragma unroll
            for (int j = 0; j < 8; ++j) {
                if (nv > j) {
                    sp += expf(p[j] - mp);
                    float et = expf(nt[j] - mt);
                    st += et;
                    w  += et * p[j];
                }
            }
            #pragma unroll
            for (int off = 32; off > 0; off >>= 1) {
                sp += __shfl_xor(sp, off, 64);
                st += __shfl_xor(st, off, 64);
                w  += __shfl_xor(w,  off, 64);
            }

            per_row = (mp + logf(sp)) - w / st;  // lse - sum(true_probs * p)
            valid   = 1.0f;
        }
    }

    // combine 4 waves -> one partial per block
    __shared__ float s_t[4];
    __shared__ float s_c[4];
    if (lane == 0) { s_t[wave] = per_row; s_c[wave] = valid; }
    __syncthreads();
    if (threadIdx.x == 0) {
        float T = s_t[0] + s_t[1] + s_t[2] + s_t[3];
        float C = s_c[0] + s_c[1] + s_c[2] + s_c[3];
        partials[blockIdx.x] = make_float2(T, C);
    }
}

__global__ __launch_bounds__(256) void listnet_finalize(
    const float2* __restrict__ partials, int n, float* __restrict__ out)
{
    float T = 0.f, C = 0.f;
    for (int i = threadIdx.x; i < n; i += 256) {
        float2 v = partials[i];
        T += v.x; C += v.y;
    }
    #pragma unroll
    for (int off = 32; off > 0; off >>= 1) {
        T += __shfl_xor(T, off, 64);
        C += __shfl_xor(C, off, 64);
    }
    __shared__ float sT[4], sC[4];
    const int wave = threadIdx.x >> 6;
    const int lane = threadIdx.x & 63;
    if (lane == 0) { sT[wave] = T; sC[wave] = C; }
    __syncthreads();
    if (threadIdx.x == 0) {
        float t = sT[0] + sT[1] + sT[2] + sT[3];
        float c = sC[0] + sC[1] + sC[2] + sC[3];
        out[0] = (c > 0.f) ? (t / fmaxf(c, 1.0f)) : 0.0f;
    }
}

extern "C" void kernel_launch(void* const* d_in, const int* in_sizes, int n_in,
                              void* d_out, int out_size, void* d_ws, size_t ws_size,
                              hipStream_t stream) {
    const float* pred    = (const float*)d_in[0];
    const float* targ    = (const float*)d_in[1];
    const int*   lengths = (const int*)d_in[2];
    const int B = in_sizes[2];                 // 16384
    const int nblocks = (B + 3) / 4;           // 4096 blocks, 4 rows each
    float2* partials = (float2*)d_ws;          // 4096 * 8B = 32 KB scratch

    listnet_rows<<<nblocks, 256, 0, stream>>>(pred, targ, lengths, partials, B);
    listnet_finalize<<<1, 256, 0, stream>>>(partials, nblocks, (float*)d_out);
}

// Round 2
// 97.784 us; speedup vs baseline: 1.0502x; 1.0502x over previous
//
#include <hip/hip_runtime.h>
#include <math.h>

#define KMAX 512  // fixed by the benchmark shapes (16384 x 512)

// One wave (64 lanes) per row. Each lane owns two float4 chunks:
//   chunk0 = elems [lane*4, lane*4+4)          (covers [0,256))
//   chunk1 = elems [256+lane*4, 256+lane*4+4)  (covers [256,512))
// L is wave-uniform, so chunk1 work is skipped with a real branch when L<=256.
// 4 rows per 256-thread block; block writes one (sum,count) partial.
__global__ __launch_bounds__(256) void listnet_rows(
    const float* __restrict__ pred,
    const float* __restrict__ targ,
    const int*   __restrict__ lengths,
    float2*      __restrict__ partials,
    int B)
{
    const int wave = threadIdx.x >> 6;
    const int lane = threadIdx.x & 63;
    const int row  = blockIdx.x * 4 + wave;

    float per_row = 0.0f;
    float valid   = 0.0f;

    if (row < B) {
        const int L = lengths[row];
        if (L >= 2) {
            const float* prow = pred + (size_t)row * KMAX;
            const float* trow = targ + (size_t)row * KMAX;
            const int e0 = lane * 4;        // chunk0 first elem
            const int e1 = 256 + e0;        // chunk1 first elem
            const int nv0 = L - e0;         // valid elems in chunk0 (<=0: none)
            const int nv1 = L - e1;         // valid elems in chunk1
            const bool two = (L > 256);     // wave-uniform

            float p0[4], t0[4], p1[4], t1[4];
            if (nv0 > 0) {
                float4 a = *reinterpret_cast<const float4*>(prow + e0);
                float4 b = *reinterpret_cast<const float4*>(trow + e0);
                p0[0]=a.x; p0[1]=a.y; p0[2]=a.z; p0[3]=a.w;
                t0[0]=-b.x; t0[1]=-b.y; t0[2]=-b.z; t0[3]=-b.w;
            }
            float mp = -INFINITY, mt = -INFINITY;
            #pragma unroll
            for (int j = 0; j < 4; ++j)
                if (nv0 > j) { mp = fmaxf(mp, p0[j]); mt = fmaxf(mt, t0[j]); }

            if (two) {
                if (nv1 > 0) {
                    float4 a = *reinterpret_cast<const float4*>(prow + e1);
                    float4 b = *reinterpret_cast<const float4*>(trow + e1);
                    p1[0]=a.x; p1[1]=a.y; p1[2]=a.z; p1[3]=a.w;
                    t1[0]=-b.x; t1[1]=-b.y; t1[2]=-b.z; t1[3]=-b.w;
                }
                #pragma unroll
                for (int j = 0; j < 4; ++j)
                    if (nv1 > j) { mp = fmaxf(mp, p1[j]); mt = fmaxf(mt, t1[j]); }
            }

            // wave-wide maxes (pair packed into one shuffle tree pass)
            #pragma unroll
            for (int off = 32; off > 0; off >>= 1) {
                mp = fmaxf(mp, __shfl_xor(mp, off, 64));
                mt = fmaxf(mt, __shfl_xor(mt, off, 64));
            }

            // sums: sp = sum exp(p-mp); st = sum exp(-t-mt); w = sum exp(-t-mt)*p
            float sp = 0.f, st = 0.f, w = 0.f;
            #pragma unroll
            for (int j = 0; j < 4; ++j) {
                if (nv0 > j) {
                    sp += __expf(p0[j] - mp);
                    float et = __expf(t0[j] - mt);
                    st += et;
                    w  += et * p0[j];
                }
            }
            if (two) {
                #pragma unroll
                for (int j = 0; j < 4; ++j) {
                    if (nv1 > j) {
                        sp += __expf(p1[j] - mp);
                        float et = __expf(t1[j] - mt);
                        st += et;
                        w  += et * p1[j];
                    }
                }
            }
            #pragma unroll
            for (int off = 32; off > 0; off >>= 1) {
                sp += __shfl_xor(sp, off, 64);
                st += __shfl_xor(st, off, 64);
                w  += __shfl_xor(w,  off, 64);
            }

            per_row = (mp + __logf(sp)) - w / st;  // lse(pred) - E_true[pred]
            valid   = 1.0f;
        }
    }

    __shared__ float s_t[4];
    __shared__ float s_c[4];
    if (lane == 0) { s_t[wave] = per_row; s_c[wave] = valid; }
    __syncthreads();
    if (threadIdx.x == 0) {
        float T = s_t[0] + s_t[1] + s_t[2] + s_t[3];
        float C = s_c[0] + s_c[1] + s_c[2] + s_c[3];
        partials[blockIdx.x] = make_float2(T, C);
    }
}

// Reduce 4096 float2 partials (read as float4 pairs) to the scalar mean.
__global__ __launch_bounds__(256) void listnet_finalize(
    const float4* __restrict__ partials4, int n4, float* __restrict__ out)
{
    float T = 0.f, C = 0.f;
    for (int i = threadIdx.x; i < n4; i += 256) {
        float4 v = partials4[i];
        T += v.x + v.z;
        C += v.y + v.w;
    }
    #pragma unroll
    for (int off = 32; off > 0; off >>= 1) {
        T += __shfl_xor(T, off, 64);
        C += __shfl_xor(C, off, 64);
    }
    __shared__ float sT[4], sC[4];
    const int wave = threadIdx.x >> 6;
    const int lane = threadIdx.x & 63;
    if (lane == 0) { sT[wave] = T; sC[wave] = C; }
    __syncthreads();
    if (threadIdx.x == 0) {
        float t = sT[0] + sT[1] + sT[2] + sT[3];
        float c = sC[0] + sC[1] + sC[2] + sC[3];
        out[0] = (c > 0.f) ? (t / fmaxf(c, 1.0f)) : 0.0f;
    }
}

extern "C" void kernel_launch(void* const* d_in, const int* in_sizes, int n_in,
                              void* d_out, int out_size, void* d_ws, size_t ws_size,
                              hipStream_t stream) {
    const float* pred    = (const float*)d_in[0];
    const float* targ    = (const float*)d_in[1];
    const int*   lengths = (const int*)d_in[2];
    const int B = in_sizes[2];                 // 16384
    const int nblocks = (B + 3) / 4;           // 4096 blocks, 4 rows each
    float2* partials = (float2*)d_ws;          // 4096 * 8B = 32 KB scratch

    listnet_rows<<<nblocks, 256, 0, stream>>>(pred, targ, lengths, partials, B);
    listnet_finalize<<<1, 256, 0, stream>>>(
        (const float4*)partials, nblocks / 2, (float*)d_out);
}